// Round 6
// baseline (360.881 us; speedup 1.0000x reference)
//
#include <hip/hip_runtime.h>

// Lowpass IIR scan: level[t] = (1-s)*x[t] + s*level[t-1], s = sigmoid(smooth).
// SINGLE-DISPATCH chunked scan with LIGHTWEIGHT inter-block sync.
// R3's lookback died (392us, VALUBusy 0.7%) because 256 thr/block all
// acquire-spun at agent scope. This version:
//   - ONE poller (tid 0) per block; others parked at __syncthreads.
//   - ONE sync address per batch: atomicOr(mask[b], 1<<c) release-publish;
//     poller spins RELAXED until low c bits all set, s_sleep between polls,
//     then ONE acquire load of the same word (release/acquire pair) +
//     __syncthreads to broadcast ordering to the block.
//   - Deadlock-free: 512 blocks all co-resident (~84 VGPR -> >=5 blocks/CU),
//     and block (c,b) only waits on earlier-dispatched lower-c blocks.
// Phase A/B bodies verbatim from R4 (verified correct, absmax 9.8e-4).
// Traffic plan (proven R3): input fetched from HBM once (phase-B re-read is
// L3-served), output written once -> ~265 MB on HBM, reads/writes interleaved
// across blocks since there is no global barrier.

typedef float f32x4 __attribute__((ext_vector_type(4)));

constexpr int B   = 16;
constexpr int T   = 2048;
constexpr int U   = 1024;
constexpr int U4  = U / 4;        // 256 float4 per row
constexpr int BU4 = B * U4;       // 4096 chain-groups

__device__ __forceinline__ float sigmoidf(float x) {
    return 1.0f / (1.0f + __expf(-x));
}

// ======================= fused single-dispatch =======================
// C fixed at 32 so the per-batch completion mask fits one uint32 exactly.
__global__ __launch_bounds__(256, 2) void lowpass_fused(
    const f32x4* __restrict__ in,      // [B*T*U4]
    const float* __restrict__ level0,  // [U]
    const float* __restrict__ smooth,  // [U]
    f32x4*       __restrict__ P,       // [32*BU4]
    unsigned*    __restrict__ mask,    // [B] completion bitmasks (zeroed)
    f32x4*       __restrict__ out)     // [B*T*U4]
{
    constexpr int C  = 32;
    constexpr int L  = T / C;         // 64
    constexpr int DA = 16;
    constexpr int DB = 8;
    constexpr int LOG2L = 6;

    const int c   = (int)blockIdx.x >> 4;   // chunk (low blockIdx = low c)
    const int b   = (int)blockIdx.x & 15;   // batch
    const int tid = (int)threadIdx.x;       // float4 column 0..255
    const int lg  = b * U4 + tid;

    const f32x4 sm = reinterpret_cast<const f32x4*>(smooth)[tid];
    const float s0 = sigmoidf(sm.x), s1 = sigmoidf(sm.y),
                s2 = sigmoidf(sm.z), s3 = sigmoidf(sm.w);
    const float o0 = 1.0f - s0, o1 = 1.0f - s1,
                o2 = 1.0f - s2, o3 = 1.0f - s3;

    const int base = (b * T + c * L) * U4 + tid;
    const f32x4* __restrict__ ip = in + base;

    // ---------------- Phase A: chunk partial (zero entry) ----------------
    float a0 = 0.0f, a1 = 0.0f, a2 = 0.0f, a3 = 0.0f;
    {
        f32x4 buf[DA];
        #pragma unroll
        for (int i = 0; i < DA; ++i) buf[i] = ip[i * U4];

        int t = 0;
        for (; t < L - DA; t += DA) {
            #pragma unroll
            for (int j = 0; j < DA; ++j) {
                f32x4 x = buf[j];
                buf[j] = ip[(t + DA + j) * U4];
                a0 = fmaf(s0, a0, o0 * x.x);
                a1 = fmaf(s1, a1, o1 * x.y);
                a2 = fmaf(s2, a2, o2 * x.z);
                a3 = fmaf(s3, a3, o3 * x.w);
            }
        }
        #pragma unroll
        for (int j = 0; j < DA; ++j) {
            f32x4 x = buf[j];
            a0 = fmaf(s0, a0, o0 * x.x);
            a1 = fmaf(s1, a1, o1 * x.y);
            a2 = fmaf(s2, a2, o2 * x.z);
            a3 = fmaf(s3, a3, o3 * x.w);
        }
    }
    f32x4 part; part.x = a0; part.y = a1; part.z = a2; part.w = a3;
    P[c * BU4 + lg] = part;

    // publish: all threads' P stores done, then one release-atomicOr
    __threadfence();                 // agent-scope release of P stores
    __syncthreads();
    if (tid == 0) {
        __hip_atomic_fetch_or(&mask[b], 1u << c,
                              __ATOMIC_RELEASE, __HIP_MEMORY_SCOPE_AGENT);
        // wait for chunks 0..c-1 of this batch (low c bits all set)
        const unsigned need = (c == 0) ? 0u : ((1u << c) - 1u);
        if (need) {
            while ((__hip_atomic_load(&mask[b], __ATOMIC_RELAXED,
                                      __HIP_MEMORY_SCOPE_AGENT) & need) != need) {
                __builtin_amdgcn_s_sleep(16);
            }
            // single acquire load pairs with publishers' release-atomicOr
            (void)__hip_atomic_load(&mask[b], __ATOMIC_ACQUIRE,
                                    __HIP_MEMORY_SCOPE_AGENT);
        }
    }
    __syncthreads();                 // broadcast ordering to the block

    // ---------------- entry level: Horner over preceding partials --------
    float sL0 = s0, sL1 = s1, sL2 = s2, sL3 = s3;
    #pragma unroll
    for (int i = 0; i < LOG2L; ++i) {
        sL0 *= sL0; sL1 *= sL1; sL2 *= sL2; sL3 *= sL3;
    }
    const f32x4 l0 = reinterpret_cast<const f32x4*>(level0)[tid];
    float v0 = l0.x, v1 = l0.y, v2 = l0.z, v3 = l0.w;
    for (int i = 0; i < c; ++i) {
        f32x4 p = P[i * BU4 + lg];
        v0 = fmaf(sL0, v0, p.x);
        v1 = fmaf(sL1, v1, p.y);
        v2 = fmaf(sL2, v2, p.z);
        v3 = fmaf(sL3, v3, p.w);
    }

    // ---------------- Phase B: scan + store (input L3-warm) --------------
    f32x4* __restrict__ op = out + base;
    f32x4 buf[DB];
    #pragma unroll
    for (int i = 0; i < DB; ++i) buf[i] = ip[i * U4];

    int t = 0;
    for (; t < L - DB; t += DB) {
        #pragma unroll
        for (int j = 0; j < DB; ++j) {
            f32x4 x = buf[j];
            buf[j] = ip[(t + DB + j) * U4];
            v0 = fmaf(s0, v0, o0 * x.x);
            v1 = fmaf(s1, v1, o1 * x.y);
            v2 = fmaf(s2, v2, o2 * x.z);
            v3 = fmaf(s3, v3, o3 * x.w);
            f32x4 r; r.x = v0; r.y = v1; r.z = v2; r.w = v3;
            __builtin_nontemporal_store(r, &op[(t + j) * U4]);
        }
    }
    #pragma unroll
    for (int j = 0; j < DB; ++j) {
        f32x4 x = buf[j];
        v0 = fmaf(s0, v0, o0 * x.x);
        v1 = fmaf(s1, v1, o1 * x.y);
        v2 = fmaf(s2, v2, o2 * x.z);
        v3 = fmaf(s3, v3, o3 * x.w);
        f32x4 r; r.x = v0; r.y = v1; r.z = v2; r.w = v3;
        __builtin_nontemporal_store(r, &op[(t + j) * U4]);
    }
}

// ============== fallback: proven two-kernel version (R4) ==============
template <int C>
__global__ __launch_bounds__(256, 2) void lowpass_partial(
    const f32x4* __restrict__ in, const float* __restrict__ smooth,
    f32x4* __restrict__ P)
{
    constexpr int L  = T / C;
    constexpr int DA = 16;
    const int c   = (int)blockIdx.x >> 4;
    const int b   = (int)blockIdx.x & 15;
    const int tid = (int)threadIdx.x;
    const int lg  = b * U4 + tid;

    const f32x4 sm = reinterpret_cast<const f32x4*>(smooth)[tid];
    const float s0 = sigmoidf(sm.x), s1 = sigmoidf(sm.y),
                s2 = sigmoidf(sm.z), s3 = sigmoidf(sm.w);
    const float o0 = 1.0f - s0, o1 = 1.0f - s1,
                o2 = 1.0f - s2, o3 = 1.0f - s3;

    const f32x4* __restrict__ ip = in + (b * T + c * L) * U4 + tid;
    float a0 = 0, a1 = 0, a2 = 0, a3 = 0;
    f32x4 buf[DA];
    #pragma unroll
    for (int i = 0; i < DA; ++i) buf[i] = ip[i * U4];
    int t = 0;
    for (; t < L - DA; t += DA) {
        #pragma unroll
        for (int j = 0; j < DA; ++j) {
            f32x4 x = buf[j];
            buf[j] = ip[(t + DA + j) * U4];
            a0 = fmaf(s0, a0, o0 * x.x); a1 = fmaf(s1, a1, o1 * x.y);
            a2 = fmaf(s2, a2, o2 * x.z); a3 = fmaf(s3, a3, o3 * x.w);
        }
    }
    #pragma unroll
    for (int j = 0; j < DA; ++j) {
        f32x4 x = buf[j];
        a0 = fmaf(s0, a0, o0 * x.x); a1 = fmaf(s1, a1, o1 * x.y);
        a2 = fmaf(s2, a2, o2 * x.z); a3 = fmaf(s3, a3, o3 * x.w);
    }
    f32x4 part; part.x = a0; part.y = a1; part.z = a2; part.w = a3;
    P[c * BU4 + lg] = part;
}

template <int C>
__global__ __launch_bounds__(256, 2) void lowpass_scan(
    const f32x4* __restrict__ in, const float* __restrict__ level0,
    const float* __restrict__ smooth, const f32x4* __restrict__ P,
    f32x4* __restrict__ out)
{
    constexpr int L  = T / C;
    constexpr int DB = 8;
    constexpr int LOG2L = 31 - __builtin_clz(L);
    const int c   = (int)blockIdx.x >> 4;
    const int b   = (int)blockIdx.x & 15;
    const int tid = (int)threadIdx.x;
    const int lg  = b * U4 + tid;

    const f32x4 sm = reinterpret_cast<const f32x4*>(smooth)[tid];
    const float s0 = sigmoidf(sm.x), s1 = sigmoidf(sm.y),
                s2 = sigmoidf(sm.z), s3 = sigmoidf(sm.w);
    const float o0 = 1.0f - s0, o1 = 1.0f - s1,
                o2 = 1.0f - s2, o3 = 1.0f - s3;

    float sL0 = s0, sL1 = s1, sL2 = s2, sL3 = s3;
    #pragma unroll
    for (int i = 0; i < LOG2L; ++i) { sL0*=sL0; sL1*=sL1; sL2*=sL2; sL3*=sL3; }

    const f32x4 l0 = reinterpret_cast<const f32x4*>(level0)[tid];
    float v0 = l0.x, v1 = l0.y, v2 = l0.z, v3 = l0.w;
    for (int i = 0; i < c; ++i) {
        f32x4 p = P[i * BU4 + lg];
        v0 = fmaf(sL0, v0, p.x); v1 = fmaf(sL1, v1, p.y);
        v2 = fmaf(sL2, v2, p.z); v3 = fmaf(sL3, v3, p.w);
    }

    const int base = (b * T + c * L) * U4 + tid;
    const f32x4* __restrict__ ip = in + base;
    f32x4* __restrict__ op = out + base;
    f32x4 buf[DB];
    #pragma unroll
    for (int i = 0; i < DB; ++i) buf[i] = ip[i * U4];
    int t = 0;
    for (; t < L - DB; t += DB) {
        #pragma unroll
        for (int j = 0; j < DB; ++j) {
            f32x4 x = buf[j];
            buf[j] = ip[(t + DB + j) * U4];
            v0 = fmaf(s0, v0, o0 * x.x); v1 = fmaf(s1, v1, o1 * x.y);
            v2 = fmaf(s2, v2, o2 * x.z); v3 = fmaf(s3, v3, o3 * x.w);
            f32x4 r; r.x = v0; r.y = v1; r.z = v2; r.w = v3;
            __builtin_nontemporal_store(r, &op[(t + j) * U4]);
        }
    }
    #pragma unroll
    for (int j = 0; j < DB; ++j) {
        f32x4 x = buf[j];
        v0 = fmaf(s0, v0, o0 * x.x); v1 = fmaf(s1, v1, o1 * x.y);
        v2 = fmaf(s2, v2, o2 * x.z); v3 = fmaf(s3, v3, o3 * x.w);
        f32x4 r; r.x = v0; r.y = v1; r.z = v2; r.w = v3;
        __builtin_nontemporal_store(r, &op[(t + j) * U4]);
    }
}

extern "C" void kernel_launch(void* const* d_in, const int* in_sizes, int n_in,
                              void* d_out, int out_size, void* d_ws, size_t ws_size,
                              hipStream_t stream) {
    const f32x4* in     = (const f32x4*)d_in[0];  // inputs [B,T,U]
    const float* level0 = (const float*)d_in[1];  // level_var [1,U]
    const float* smooth = (const float*)d_in[2];  // smoothing_var [1,U]
    f32x4* out          = (f32x4*)d_out;
    f32x4* P            = (f32x4*)d_ws;

    const size_t pBytes = (size_t)32 * BU4 * sizeof(f32x4);   // 2 MiB

    if (ws_size >= pBytes + B * sizeof(unsigned)) {
        unsigned* mask = (unsigned*)((char*)d_ws + pBytes);
        (void)hipMemsetAsync(mask, 0, B * sizeof(unsigned), stream);
        hipLaunchKernelGGL(lowpass_fused, dim3(32 * B), dim3(256), 0, stream,
                           in, level0, smooth, P, mask, out);
    } else {                                                  // 512 KiB fallback
        constexpr int C = 8;
        dim3 grid(C * B);
        hipLaunchKernelGGL(lowpass_partial<C>, grid, dim3(256), 0, stream,
                           in, smooth, P);
        hipLaunchKernelGGL(lowpass_scan<C>,    grid, dim3(256), 0, stream,
                           in, level0, smooth, P, out);
    }
}

// Round 7
// 350.894 us; speedup vs baseline: 1.0285x; 1.0285x over previous
//
#include <hip/hip_runtime.h>

// Lowpass IIR scan: level[t] = (1-s)*x[t] + s*level[t-1], s = sigmoid(smooth).
// SINGLE-DISPATCH chunked scan with lightweight inter-block sync, v3.
// History: R3 (256 pollers/block, agent-acquire spin) = 392us sync storm.
//          R6 (1 poller/block, relaxed spin) = 205us; sync still ~130us.
// R6 diagnosis: all 16 batch flags shared ONE 64B cache line (false sharing
// at the memory-side atomic point) + 0.43us poll period -> serialized polls.
// v3 fix (logic identical to R6, which passed): 
//   - flags padded to 128B per batch (32 uints) -> no line sharing
//   - s_sleep(127) ~= 3.4us poll period -> ~10 polls per waiting block
// Phase A/B bodies verbatim from R4/R6 (verified, absmax 9.8e-4).
// Traffic (proven R3/R6): input fetched from HBM once (phase-B re-read is
// L3-served), output written once, ~265MB total on HBM.

typedef float f32x4 __attribute__((ext_vector_type(4)));

constexpr int B   = 16;
constexpr int T   = 2048;
constexpr int U   = 1024;
constexpr int U4  = U / 4;        // 256 float4 per row
constexpr int BU4 = B * U4;       // 4096 chain-groups
constexpr int FLAG_STRIDE = 32;   // uints per batch flag slot (128 B)

__device__ __forceinline__ float sigmoidf(float x) {
    return 1.0f / (1.0f + __expf(-x));
}

// ======================= fused single-dispatch =======================
// C fixed at 32 so the per-batch completion mask fits one uint32 exactly.
__global__ __launch_bounds__(256, 2) void lowpass_fused(
    const f32x4* __restrict__ in,      // [B*T*U4]
    const float* __restrict__ level0,  // [U]
    const float* __restrict__ smooth,  // [U]
    f32x4*       __restrict__ P,       // [32*BU4]
    unsigned*    __restrict__ mask,    // [B*FLAG_STRIDE], zeroed; word b*32
    f32x4*       __restrict__ out)     // [B*T*U4]
{
    constexpr int C  = 32;
    constexpr int L  = T / C;         // 64
    constexpr int DA = 16;
    constexpr int DB = 8;
    constexpr int LOG2L = 6;

    const int c   = (int)blockIdx.x >> 4;   // chunk (low blockIdx = low c)
    const int b   = (int)blockIdx.x & 15;   // batch
    const int tid = (int)threadIdx.x;       // float4 column 0..255
    const int lg  = b * U4 + tid;
    unsigned* const flag = &mask[b * FLAG_STRIDE];  // own 128B line per batch

    const f32x4 sm = reinterpret_cast<const f32x4*>(smooth)[tid];
    const float s0 = sigmoidf(sm.x), s1 = sigmoidf(sm.y),
                s2 = sigmoidf(sm.z), s3 = sigmoidf(sm.w);
    const float o0 = 1.0f - s0, o1 = 1.0f - s1,
                o2 = 1.0f - s2, o3 = 1.0f - s3;

    const int base = (b * T + c * L) * U4 + tid;
    const f32x4* __restrict__ ip = in + base;

    // ---------------- Phase A: chunk partial (zero entry) ----------------
    float a0 = 0.0f, a1 = 0.0f, a2 = 0.0f, a3 = 0.0f;
    {
        f32x4 buf[DA];
        #pragma unroll
        for (int i = 0; i < DA; ++i) buf[i] = ip[i * U4];

        int t = 0;
        for (; t < L - DA; t += DA) {
            #pragma unroll
            for (int j = 0; j < DA; ++j) {
                f32x4 x = buf[j];
                buf[j] = ip[(t + DA + j) * U4];
                a0 = fmaf(s0, a0, o0 * x.x);
                a1 = fmaf(s1, a1, o1 * x.y);
                a2 = fmaf(s2, a2, o2 * x.z);
                a3 = fmaf(s3, a3, o3 * x.w);
            }
        }
        #pragma unroll
        for (int j = 0; j < DA; ++j) {
            f32x4 x = buf[j];
            a0 = fmaf(s0, a0, o0 * x.x);
            a1 = fmaf(s1, a1, o1 * x.y);
            a2 = fmaf(s2, a2, o2 * x.z);
            a3 = fmaf(s3, a3, o3 * x.w);
        }
    }
    f32x4 part; part.x = a0; part.y = a1; part.z = a2; part.w = a3;
    P[c * BU4 + lg] = part;

    // publish: all threads' P stores done, then one release-atomicOr
    __threadfence();                 // agent-scope release of P stores
    __syncthreads();
    if (tid == 0) {
        __hip_atomic_fetch_or(flag, 1u << c,
                              __ATOMIC_RELEASE, __HIP_MEMORY_SCOPE_AGENT);
        // wait for chunks 0..c-1 of this batch (low c bits all set)
        const unsigned need = (c == 0) ? 0u : ((1u << c) - 1u);
        if (need) {
            while ((__hip_atomic_load(flag, __ATOMIC_RELAXED,
                                      __HIP_MEMORY_SCOPE_AGENT) & need) != need) {
                __builtin_amdgcn_s_sleep(127);   // ~3.4us between polls
            }
            // single acquire load pairs with publishers' release-atomicOr
            (void)__hip_atomic_load(flag, __ATOMIC_ACQUIRE,
                                    __HIP_MEMORY_SCOPE_AGENT);
        }
    }
    __syncthreads();                 // broadcast ordering to the block

    // ---------------- entry level: Horner over preceding partials --------
    float sL0 = s0, sL1 = s1, sL2 = s2, sL3 = s3;
    #pragma unroll
    for (int i = 0; i < LOG2L; ++i) {
        sL0 *= sL0; sL1 *= sL1; sL2 *= sL2; sL3 *= sL3;
    }
    const f32x4 l0 = reinterpret_cast<const f32x4*>(level0)[tid];
    float v0 = l0.x, v1 = l0.y, v2 = l0.z, v3 = l0.w;
    for (int i = 0; i < c; ++i) {
        f32x4 p = P[i * BU4 + lg];
        v0 = fmaf(sL0, v0, p.x);
        v1 = fmaf(sL1, v1, p.y);
        v2 = fmaf(sL2, v2, p.z);
        v3 = fmaf(sL3, v3, p.w);
    }

    // ---------------- Phase B: scan + store (input L3-warm) --------------
    f32x4* __restrict__ op = out + base;
    f32x4 buf[DB];
    #pragma unroll
    for (int i = 0; i < DB; ++i) buf[i] = ip[i * U4];

    int t = 0;
    for (; t < L - DB; t += DB) {
        #pragma unroll
        for (int j = 0; j < DB; ++j) {
            f32x4 x = buf[j];
            buf[j] = ip[(t + DB + j) * U4];
            v0 = fmaf(s0, v0, o0 * x.x);
            v1 = fmaf(s1, v1, o1 * x.y);
            v2 = fmaf(s2, v2, o2 * x.z);
            v3 = fmaf(s3, v3, o3 * x.w);
            f32x4 r; r.x = v0; r.y = v1; r.z = v2; r.w = v3;
            __builtin_nontemporal_store(r, &op[(t + j) * U4]);
        }
    }
    #pragma unroll
    for (int j = 0; j < DB; ++j) {
        f32x4 x = buf[j];
        v0 = fmaf(s0, v0, o0 * x.x);
        v1 = fmaf(s1, v1, o1 * x.y);
        v2 = fmaf(s2, v2, o2 * x.z);
        v3 = fmaf(s3, v3, o3 * x.w);
        f32x4 r; r.x = v0; r.y = v1; r.z = v2; r.w = v3;
        __builtin_nontemporal_store(r, &op[(t + j) * U4]);
    }
}

// ============== fallback: proven two-kernel version (R4) ==============
template <int C>
__global__ __launch_bounds__(256, 2) void lowpass_partial(
    const f32x4* __restrict__ in, const float* __restrict__ smooth,
    f32x4* __restrict__ P)
{
    constexpr int L  = T / C;
    constexpr int DA = 16;
    const int c   = (int)blockIdx.x >> 4;
    const int b   = (int)blockIdx.x & 15;
    const int tid = (int)threadIdx.x;
    const int lg  = b * U4 + tid;

    const f32x4 sm = reinterpret_cast<const f32x4*>(smooth)[tid];
    const float s0 = sigmoidf(sm.x), s1 = sigmoidf(sm.y),
                s2 = sigmoidf(sm.z), s3 = sigmoidf(sm.w);
    const float o0 = 1.0f - s0, o1 = 1.0f - s1,
                o2 = 1.0f - s2, o3 = 1.0f - s3;

    const f32x4* __restrict__ ip = in + (b * T + c * L) * U4 + tid;
    float a0 = 0, a1 = 0, a2 = 0, a3 = 0;
    f32x4 buf[DA];
    #pragma unroll
    for (int i = 0; i < DA; ++i) buf[i] = ip[i * U4];
    int t = 0;
    for (; t < L - DA; t += DA) {
        #pragma unroll
        for (int j = 0; j < DA; ++j) {
            f32x4 x = buf[j];
            buf[j] = ip[(t + DA + j) * U4];
            a0 = fmaf(s0, a0, o0 * x.x); a1 = fmaf(s1, a1, o1 * x.y);
            a2 = fmaf(s2, a2, o2 * x.z); a3 = fmaf(s3, a3, o3 * x.w);
        }
    }
    #pragma unroll
    for (int j = 0; j < DA; ++j) {
        f32x4 x = buf[j];
        a0 = fmaf(s0, a0, o0 * x.x); a1 = fmaf(s1, a1, o1 * x.y);
        a2 = fmaf(s2, a2, o2 * x.z); a3 = fmaf(s3, a3, o3 * x.w);
    }
    f32x4 part; part.x = a0; part.y = a1; part.z = a2; part.w = a3;
    P[c * BU4 + lg] = part;
}

template <int C>
__global__ __launch_bounds__(256, 2) void lowpass_scan(
    const f32x4* __restrict__ in, const float* __restrict__ level0,
    const float* __restrict__ smooth, const f32x4* __restrict__ P,
    f32x4* __restrict__ out)
{
    constexpr int L  = T / C;
    constexpr int DB = 8;
    constexpr int LOG2L = 31 - __builtin_clz(L);
    const int c   = (int)blockIdx.x >> 4;
    const int b   = (int)blockIdx.x & 15;
    const int tid = (int)threadIdx.x;
    const int lg  = b * U4 + tid;

    const f32x4 sm = reinterpret_cast<const f32x4*>(smooth)[tid];
    const float s0 = sigmoidf(sm.x), s1 = sigmoidf(sm.y),
                s2 = sigmoidf(sm.z), s3 = sigmoidf(sm.w);
    const float o0 = 1.0f - s0, o1 = 1.0f - s1,
                o2 = 1.0f - s2, o3 = 1.0f - s3;

    float sL0 = s0, sL1 = s1, sL2 = s2, sL3 = s3;
    #pragma unroll
    for (int i = 0; i < LOG2L; ++i) { sL0*=sL0; sL1*=sL1; sL2*=sL2; sL3*=sL3; }

    const f32x4 l0 = reinterpret_cast<const f32x4*>(level0)[tid];
    float v0 = l0.x, v1 = l0.y, v2 = l0.z, v3 = l0.w;
    for (int i = 0; i < c; ++i) {
        f32x4 p = P[i * BU4 + lg];
        v0 = fmaf(sL0, v0, p.x); v1 = fmaf(sL1, v1, p.y);
        v2 = fmaf(sL2, v2, p.z); v3 = fmaf(sL3, v3, p.w);
    }

    const int base = (b * T + c * L) * U4 + tid;
    const f32x4* __restrict__ ip = in + base;
    f32x4* __restrict__ op = out + base;
    f32x4 buf[DB];
    #pragma unroll
    for (int i = 0; i < DB; ++i) buf[i] = ip[i * U4];
    int t = 0;
    for (; t < L - DB; t += DB) {
        #pragma unroll
        for (int j = 0; j < DB; ++j) {
            f32x4 x = buf[j];
            buf[j] = ip[(t + DB + j) * U4];
            v0 = fmaf(s0, v0, o0 * x.x); v1 = fmaf(s1, v1, o1 * x.y);
            v2 = fmaf(s2, v2, o2 * x.z); v3 = fmaf(s3, v3, o3 * x.w);
            f32x4 r; r.x = v0; r.y = v1; r.z = v2; r.w = v3;
            __builtin_nontemporal_store(r, &op[(t + j) * U4]);
        }
    }
    #pragma unroll
    for (int j = 0; j < DB; ++j) {
        f32x4 x = buf[j];
        v0 = fmaf(s0, v0, o0 * x.x); v1 = fmaf(s1, v1, o1 * x.y);
        v2 = fmaf(s2, v2, o2 * x.z); v3 = fmaf(s3, v3, o3 * x.w);
        f32x4 r; r.x = v0; r.y = v1; r.z = v2; r.w = v3;
        __builtin_nontemporal_store(r, &op[(t + j) * U4]);
    }
}

extern "C" void kernel_launch(void* const* d_in, const int* in_sizes, int n_in,
                              void* d_out, int out_size, void* d_ws, size_t ws_size,
                              hipStream_t stream) {
    const f32x4* in     = (const f32x4*)d_in[0];  // inputs [B,T,U]
    const float* level0 = (const float*)d_in[1];  // level_var [1,U]
    const float* smooth = (const float*)d_in[2];  // smoothing_var [1,U]
    f32x4* out          = (f32x4*)d_out;
    f32x4* P            = (f32x4*)d_ws;

    const size_t pBytes = (size_t)32 * BU4 * sizeof(f32x4);   // 2 MiB
    const size_t fBytes = (size_t)B * FLAG_STRIDE * sizeof(unsigned);  // 2 KiB

    if (ws_size >= pBytes + fBytes) {
        unsigned* mask = (unsigned*)((char*)d_ws + pBytes);
        (void)hipMemsetAsync(mask, 0, fBytes, stream);
        hipLaunchKernelGGL(lowpass_fused, dim3(32 * B), dim3(256), 0, stream,
                           in, level0, smooth, P, mask, out);
    } else {                                                  // 512 KiB fallback
        constexpr int C = 8;
        dim3 grid(C * B);
        hipLaunchKernelGGL(lowpass_partial<C>, grid, dim3(256), 0, stream,
                           in, smooth, P);
        hipLaunchKernelGGL(lowpass_scan<C>,    grid, dim3(256), 0, stream,
                           in, level0, smooth, P, out);
    }
}

// Round 8
// 254.151 us; speedup vs baseline: 1.4199x; 1.3807x over previous
//
#include <hip/hip_runtime.h>

// Lowpass IIR scan: level[t] = (1-s)*x[t] + s*level[t-1], s = sigmoid(smooth).
// SINGLE-DISPATCH chunked scan, sync v4: ZERO cache-maintenance ops.
// History: R3 per-thread acquire spin = 392us (buffer_inv per poll).
//          R6 one poller + release/acquire + threadfence = 205us.
//          R7 padded flags + slow poll = 199us (null) -> polling wasn't it.
// v4 theory: the cost is __threadfence (buffer_wbl2, per-wave x2048) and
// acquire loads (buffer_inv, whole-L2 invalidate x512, which also evicts the
// input before phase B re-reads it). Fix: pass P + flags through the
// memory-side coherence point with RELAXED agent-scope atomics (sc0 sc1
// cache-bypass, no wbl2/inv). Ordering anchored by __syncthreads on both
// sides (drains vmcnt before flag publish; compiler fence). Consumer's P
// loads bypass caches so they can't read stale lines.
// Phase A/B bodies verbatim from R4/R6 (verified, absmax 9.8e-4).

typedef float f32x4 __attribute__((ext_vector_type(4)));

constexpr int B   = 16;
constexpr int T   = 2048;
constexpr int U   = 1024;
constexpr int U4  = U / 4;        // 256 float4 per row
constexpr int BU4 = B * U4;       // 4096 chain-groups
constexpr int FLAG_STRIDE = 32;   // uints per batch flag slot (128 B)

__device__ __forceinline__ float sigmoidf(float x) {
    return 1.0f / (1.0f + __expf(-x));
}

// ======================= fused single-dispatch =======================
// C fixed at 32 so the per-batch completion mask fits one uint32 exactly.
__global__ __launch_bounds__(256, 2) void lowpass_fused(
    const f32x4* __restrict__ in,      // [B*T*U4]
    const float* __restrict__ level0,  // [U]
    const float* __restrict__ smooth,  // [U]
    float*       __restrict__ Pf,      // [32*BU4*4] floats (bypass-accessed)
    unsigned*    __restrict__ mask,    // [B*FLAG_STRIDE], zeroed; word b*32
    f32x4*       __restrict__ out)     // [B*T*U4]
{
    constexpr int C  = 32;
    constexpr int L  = T / C;         // 64
    constexpr int DA = 16;
    constexpr int DB = 8;
    constexpr int LOG2L = 6;

    const int c   = (int)blockIdx.x >> 4;   // chunk (low blockIdx = low c)
    const int b   = (int)blockIdx.x & 15;   // batch
    const int tid = (int)threadIdx.x;       // float4 column 0..255
    const int lg  = b * U4 + tid;
    unsigned* const flag = &mask[b * FLAG_STRIDE];  // own 128B line per batch

    const f32x4 sm = reinterpret_cast<const f32x4*>(smooth)[tid];
    const float s0 = sigmoidf(sm.x), s1 = sigmoidf(sm.y),
                s2 = sigmoidf(sm.z), s3 = sigmoidf(sm.w);
    const float o0 = 1.0f - s0, o1 = 1.0f - s1,
                o2 = 1.0f - s2, o3 = 1.0f - s3;

    const int base = (b * T + c * L) * U4 + tid;
    const f32x4* __restrict__ ip = in + base;

    // ---------------- Phase A: chunk partial (zero entry) ----------------
    float a0 = 0.0f, a1 = 0.0f, a2 = 0.0f, a3 = 0.0f;
    {
        f32x4 buf[DA];
        #pragma unroll
        for (int i = 0; i < DA; ++i) buf[i] = ip[i * U4];

        int t = 0;
        for (; t < L - DA; t += DA) {
            #pragma unroll
            for (int j = 0; j < DA; ++j) {
                f32x4 x = buf[j];
                buf[j] = ip[(t + DA + j) * U4];
                a0 = fmaf(s0, a0, o0 * x.x);
                a1 = fmaf(s1, a1, o1 * x.y);
                a2 = fmaf(s2, a2, o2 * x.z);
                a3 = fmaf(s3, a3, o3 * x.w);
            }
        }
        #pragma unroll
        for (int j = 0; j < DA; ++j) {
            f32x4 x = buf[j];
            a0 = fmaf(s0, a0, o0 * x.x);
            a1 = fmaf(s1, a1, o1 * x.y);
            a2 = fmaf(s2, a2, o2 * x.z);
            a3 = fmaf(s3, a3, o3 * x.w);
        }
    }
    // publish partial via cache-bypass stores (coalesced: 4 consecutive
    // floats per thread). No threadfence, no wbl2.
    {
        const size_t po = ((size_t)c * BU4 + lg) * 4;
        __hip_atomic_store(&Pf[po + 0], a0, __ATOMIC_RELAXED, __HIP_MEMORY_SCOPE_AGENT);
        __hip_atomic_store(&Pf[po + 1], a1, __ATOMIC_RELAXED, __HIP_MEMORY_SCOPE_AGENT);
        __hip_atomic_store(&Pf[po + 2], a2, __ATOMIC_RELAXED, __HIP_MEMORY_SCOPE_AGENT);
        __hip_atomic_store(&Pf[po + 3], a3, __ATOMIC_RELAXED, __HIP_MEMORY_SCOPE_AGENT);
    }

    // __syncthreads: every wave drains vmcnt(0) before the barrier -> all
    // P stores are memory-acked before tid0 publishes the flag.
    __syncthreads();
    if (tid == 0) {
        __hip_atomic_fetch_or(flag, 1u << c,
                              __ATOMIC_RELAXED, __HIP_MEMORY_SCOPE_AGENT);
        // wait for chunks 0..c-1 of this batch (low c bits all set)
        const unsigned need = (c == 0) ? 0u : ((1u << c) - 1u);
        if (need) {
            while ((__hip_atomic_load(flag, __ATOMIC_RELAXED,
                                      __HIP_MEMORY_SCOPE_AGENT) & need) != need) {
                __builtin_amdgcn_s_sleep(32);   // ~1us between polls
            }
        }
    }
    __syncthreads();                 // compiler+HW fence; block proceeds

    // ---------------- entry level: Horner over preceding partials --------
    float sL0 = s0, sL1 = s1, sL2 = s2, sL3 = s3;
    #pragma unroll
    for (int i = 0; i < LOG2L; ++i) {
        sL0 *= sL0; sL1 *= sL1; sL2 *= sL2; sL3 *= sL3;
    }
    const f32x4 l0 = reinterpret_cast<const f32x4*>(level0)[tid];
    float v0 = l0.x, v1 = l0.y, v2 = l0.z, v3 = l0.w;
    for (int i = 0; i < c; ++i) {
        // cache-bypass loads: cannot hit stale lines (never cached)
        const size_t po = ((size_t)i * BU4 + lg) * 4;
        float px = __hip_atomic_load(&Pf[po + 0], __ATOMIC_RELAXED, __HIP_MEMORY_SCOPE_AGENT);
        float py = __hip_atomic_load(&Pf[po + 1], __ATOMIC_RELAXED, __HIP_MEMORY_SCOPE_AGENT);
        float pz = __hip_atomic_load(&Pf[po + 2], __ATOMIC_RELAXED, __HIP_MEMORY_SCOPE_AGENT);
        float pw = __hip_atomic_load(&Pf[po + 3], __ATOMIC_RELAXED, __HIP_MEMORY_SCOPE_AGENT);
        v0 = fmaf(sL0, v0, px);
        v1 = fmaf(sL1, v1, py);
        v2 = fmaf(sL2, v2, pz);
        v3 = fmaf(sL3, v3, pw);
    }

    // ---------------- Phase B: scan + store (input L2/L3-warm) -----------
    f32x4* __restrict__ op = out + base;
    f32x4 buf[DB];
    #pragma unroll
    for (int i = 0; i < DB; ++i) buf[i] = ip[i * U4];

    int t = 0;
    for (; t < L - DB; t += DB) {
        #pragma unroll
        for (int j = 0; j < DB; ++j) {
            f32x4 x = buf[j];
            buf[j] = ip[(t + DB + j) * U4];
            v0 = fmaf(s0, v0, o0 * x.x);
            v1 = fmaf(s1, v1, o1 * x.y);
            v2 = fmaf(s2, v2, o2 * x.z);
            v3 = fmaf(s3, v3, o3 * x.w);
            f32x4 r; r.x = v0; r.y = v1; r.z = v2; r.w = v3;
            __builtin_nontemporal_store(r, &op[(t + j) * U4]);
        }
    }
    #pragma unroll
    for (int j = 0; j < DB; ++j) {
        f32x4 x = buf[j];
        v0 = fmaf(s0, v0, o0 * x.x);
        v1 = fmaf(s1, v1, o1 * x.y);
        v2 = fmaf(s2, v2, o2 * x.z);
        v3 = fmaf(s3, v3, o3 * x.w);
        f32x4 r; r.x = v0; r.y = v1; r.z = v2; r.w = v3;
        __builtin_nontemporal_store(r, &op[(t + j) * U4]);
    }
}

// ============== fallback: proven two-kernel version (R4) ==============
template <int C>
__global__ __launch_bounds__(256, 2) void lowpass_partial(
    const f32x4* __restrict__ in, const float* __restrict__ smooth,
    f32x4* __restrict__ P)
{
    constexpr int L  = T / C;
    constexpr int DA = 16;
    const int c   = (int)blockIdx.x >> 4;
    const int b   = (int)blockIdx.x & 15;
    const int tid = (int)threadIdx.x;
    const int lg  = b * U4 + tid;

    const f32x4 sm = reinterpret_cast<const f32x4*>(smooth)[tid];
    const float s0 = sigmoidf(sm.x), s1 = sigmoidf(sm.y),
                s2 = sigmoidf(sm.z), s3 = sigmoidf(sm.w);
    const float o0 = 1.0f - s0, o1 = 1.0f - s1,
                o2 = 1.0f - s2, o3 = 1.0f - s3;

    const f32x4* __restrict__ ip = in + (b * T + c * L) * U4 + tid;
    float a0 = 0, a1 = 0, a2 = 0, a3 = 0;
    f32x4 buf[DA];
    #pragma unroll
    for (int i = 0; i < DA; ++i) buf[i] = ip[i * U4];
    int t = 0;
    for (; t < L - DA; t += DA) {
        #pragma unroll
        for (int j = 0; j < DA; ++j) {
            f32x4 x = buf[j];
            buf[j] = ip[(t + DA + j) * U4];
            a0 = fmaf(s0, a0, o0 * x.x); a1 = fmaf(s1, a1, o1 * x.y);
            a2 = fmaf(s2, a2, o2 * x.z); a3 = fmaf(s3, a3, o3 * x.w);
        }
    }
    #pragma unroll
    for (int j = 0; j < DA; ++j) {
        f32x4 x = buf[j];
        a0 = fmaf(s0, a0, o0 * x.x); a1 = fmaf(s1, a1, o1 * x.y);
        a2 = fmaf(s2, a2, o2 * x.z); a3 = fmaf(s3, a3, o3 * x.w);
    }
    f32x4 part; part.x = a0; part.y = a1; part.z = a2; part.w = a3;
    P[c * BU4 + lg] = part;
}

template <int C>
__global__ __launch_bounds__(256, 2) void lowpass_scan(
    const f32x4* __restrict__ in, const float* __restrict__ level0,
    const float* __restrict__ smooth, const f32x4* __restrict__ P,
    f32x4* __restrict__ out)
{
    constexpr int L  = T / C;
    constexpr int DB = 8;
    constexpr int LOG2L = 31 - __builtin_clz(L);
    const int c   = (int)blockIdx.x >> 4;
    const int b   = (int)blockIdx.x & 15;
    const int tid = (int)threadIdx.x;
    const int lg  = b * U4 + tid;

    const f32x4 sm = reinterpret_cast<const f32x4*>(smooth)[tid];
    const float s0 = sigmoidf(sm.x), s1 = sigmoidf(sm.y),
                s2 = sigmoidf(sm.z), s3 = sigmoidf(sm.w);
    const float o0 = 1.0f - s0, o1 = 1.0f - s1,
                o2 = 1.0f - s2, o3 = 1.0f - s3;

    float sL0 = s0, sL1 = s1, sL2 = s2, sL3 = s3;
    #pragma unroll
    for (int i = 0; i < LOG2L; ++i) { sL0*=sL0; sL1*=sL1; sL2*=sL2; sL3*=sL3; }

    const f32x4 l0 = reinterpret_cast<const f32x4*>(level0)[tid];
    float v0 = l0.x, v1 = l0.y, v2 = l0.z, v3 = l0.w;
    for (int i = 0; i < c; ++i) {
        f32x4 p = P[i * BU4 + lg];
        v0 = fmaf(sL0, v0, p.x); v1 = fmaf(sL1, v1, p.y);
        v2 = fmaf(sL2, v2, p.z); v3 = fmaf(sL3, v3, p.w);
    }

    const int base = (b * T + c * L) * U4 + tid;
    const f32x4* __restrict__ ip = in + base;
    f32x4* __restrict__ op = out + base;
    f32x4 buf[DB];
    #pragma unroll
    for (int i = 0; i < DB; ++i) buf[i] = ip[i * U4];
    int t = 0;
    for (; t < L - DB; t += DB) {
        #pragma unroll
        for (int j = 0; j < DB; ++j) {
            f32x4 x = buf[j];
            buf[j] = ip[(t + DB + j) * U4];
            v0 = fmaf(s0, v0, o0 * x.x); v1 = fmaf(s1, v1, o1 * x.y);
            v2 = fmaf(s2, v2, o2 * x.z); v3 = fmaf(s3, v3, o3 * x.w);
            f32x4 r; r.x = v0; r.y = v1; r.z = v2; r.w = v3;
            __builtin_nontemporal_store(r, &op[(t + j) * U4]);
        }
    }
    #pragma unroll
    for (int j = 0; j < DB; ++j) {
        f32x4 x = buf[j];
        v0 = fmaf(s0, v0, o0 * x.x); v1 = fmaf(s1, v1, o1 * x.y);
        v2 = fmaf(s2, v2, o2 * x.z); v3 = fmaf(s3, v3, o3 * x.w);
        f32x4 r; r.x = v0; r.y = v1; r.z = v2; r.w = v3;
        __builtin_nontemporal_store(r, &op[(t + j) * U4]);
    }
}

extern "C" void kernel_launch(void* const* d_in, const int* in_sizes, int n_in,
                              void* d_out, int out_size, void* d_ws, size_t ws_size,
                              hipStream_t stream) {
    const f32x4* in     = (const f32x4*)d_in[0];  // inputs [B,T,U]
    const float* level0 = (const float*)d_in[1];  // level_var [1,U]
    const float* smooth = (const float*)d_in[2];  // smoothing_var [1,U]
    f32x4* out          = (f32x4*)d_out;

    const size_t pBytes = (size_t)32 * BU4 * sizeof(f32x4);   // 2 MiB
    const size_t fBytes = (size_t)B * FLAG_STRIDE * sizeof(unsigned);  // 2 KiB

    if (ws_size >= pBytes + fBytes) {
        float* Pf      = (float*)d_ws;
        unsigned* mask = (unsigned*)((char*)d_ws + pBytes);
        (void)hipMemsetAsync(mask, 0, fBytes, stream);
        hipLaunchKernelGGL(lowpass_fused, dim3(32 * B), dim3(256), 0, stream,
                           in, level0, smooth, Pf, mask, out);
    } else {                                                  // 512 KiB fallback
        constexpr int C = 8;
        f32x4* P = (f32x4*)d_ws;
        dim3 grid(C * B);
        hipLaunchKernelGGL(lowpass_partial<C>, grid, dim3(256), 0, stream,
                           in, smooth, P);
        hipLaunchKernelGGL(lowpass_scan<C>,    grid, dim3(256), 0, stream,
                           in, level0, smooth, P, out);
    }
}